// Round 4
// baseline (526.481 us; speedup 1.0000x reference)
//
#include <hip/hip_runtime.h>
#include <stdint.h>

// ---------------------------------------------------------------------------
// CrossAttentionRope: x(16,256,768), ctx(16,4096,768) f32 -> out(16,256,768) f32
// R4: GEMMs reverted to R2 (reg-staged + XOR swizzle, proven). attn rebuilt on
//     16x16x32 MFMA (all layouts verified by passing rounds): swapped QK^T
//     (lane owns q=lc, kv spread over g,r), 2-shfl softmax, P packed in-reg
//     (zero cross-lane) with V LDS column-permutation to match, no P LDS.
// ---------------------------------------------------------------------------

typedef __bf16 bf16x8 __attribute__((ext_vector_type(8)));
typedef unsigned short u16x8 __attribute__((ext_vector_type(8)));
typedef unsigned short u16x4 __attribute__((ext_vector_type(4)));
typedef float f32x4 __attribute__((ext_vector_type(4)));

#define DIMF 768
#define NHEAD 12
#define NKV 4096
#define NQ 256
#define NB 16

struct alignas(8) us4 { unsigned short x, y, z, w; };

__device__ __forceinline__ unsigned short f2bf(float x) {
  uint32_t u = __float_as_uint(x);
  u += 0x7fffu + ((u >> 16) & 1u);   // round-to-nearest-even
  return (unsigned short)(u >> 16);
}

// ---------------- convert f32 -> bf16 (vectorized, grid-stride) ------------
__global__ void cvt_kernel(const float* __restrict__ in, unsigned short* __restrict__ out, int n) {
  int stride = gridDim.x * blockDim.x * 4;
  for (int i = (blockIdx.x * blockDim.x + threadIdx.x) * 4; i < n; i += stride) {
    float4 v = *(const float4*)(in + i);
    us4 o{f2bf(v.x), f2bf(v.y), f2bf(v.z), f2bf(v.w)};
    *(us4*)(out + i) = o;
  }
}

// ---------------- weight transpose + cvt: Wt[n][k] = W[k][n] ---------------
__global__ void twt_kernel(const float* __restrict__ W0, const float* __restrict__ W1,
                           const float* __restrict__ W2, const float* __restrict__ W3,
                           unsigned short* __restrict__ O0, unsigned short* __restrict__ O1,
                           unsigned short* __restrict__ O2, unsigned short* __restrict__ O3) {
  const float* W; unsigned short* O;
  switch (blockIdx.z) {
    case 0: W = W0; O = O0; break;
    case 1: W = W1; O = O1; break;
    case 2: W = W2; O = O2; break;
    default: W = W3; O = O3; break;
  }
  __shared__ float t[32][33];
  int x0 = blockIdx.x * 32, y0 = blockIdx.y * 32;
  int tx = threadIdx.x, ty = threadIdx.y;
#pragma unroll
  for (int j = 0; j < 4; ++j)
    t[ty + 8 * j][tx] = W[(size_t)(y0 + ty + 8 * j) * DIMF + x0 + tx];
  __syncthreads();
#pragma unroll
  for (int j = 0; j < 4; ++j)
    O[(size_t)(x0 + ty + 8 * j) * DIMF + y0 + tx] = f2bf(t[tx][ty + 8 * j]);
}

// ---------------- GEMM (R2-proven): C(128x128) = A(Mx768) * Bt(768x768)^T ---
template <int MODE>
__launch_bounds__(256, 2)
__global__ void gemm_kernel(const unsigned short* __restrict__ A,
                            const unsigned short* __restrict__ Bt,
                            void* __restrict__ outp,
                            const float* __restrict__ rope) {
  __shared__ unsigned short As[128 * 64];
  __shared__ unsigned short Bs[128 * 64];
  const int t = threadIdx.x;
  const int lane = t & 63, wid = t >> 6;
  const int g = lane >> 4, lc = lane & 15;
  const int wr = wid >> 1, wc = wid & 1;
  const int rowBase = blockIdx.x * 128, colBase = blockIdx.y * 128;

  const f32x4 z4 = {0.f, 0.f, 0.f, 0.f};
  f32x4 acc[4][4];
#pragma unroll
  for (int m = 0; m < 4; ++m)
#pragma unroll
    for (int n = 0; n < 4; ++n) acc[m][n] = z4;

  const int r0 = t >> 3;   // 0..31
  const int c0 = t & 7;    // 16B chunk within 128B row

  bf16x8 ra[4], rb[4];
#pragma unroll
  for (int pp = 0; pp < 4; ++pp) {
    int row = pp * 32 + r0;
    ra[pp] = *(const bf16x8*)(A + (size_t)(rowBase + row) * DIMF + c0 * 8);
    rb[pp] = *(const bf16x8*)(Bt + (size_t)(colBase + row) * DIMF + c0 * 8);
  }

  for (int kb = 0; kb < 12; ++kb) {
    __syncthreads();
#pragma unroll
    for (int pp = 0; pp < 4; ++pp) {
      int row = pp * 32 + r0;
      int ph = ((c0 ^ (row & 7)) << 3);
      *(bf16x8*)&As[row * 64 + ph] = ra[pp];
      *(bf16x8*)&Bs[row * 64 + ph] = rb[pp];
    }
    __syncthreads();
    if (kb + 1 < 12) {
      int kn = (kb + 1) * 64;
#pragma unroll
      for (int pp = 0; pp < 4; ++pp) {
        int row = pp * 32 + r0;
        ra[pp] = *(const bf16x8*)(A + (size_t)(rowBase + row) * DIMF + kn + c0 * 8);
        rb[pp] = *(const bf16x8*)(Bt + (size_t)(colBase + row) * DIMF + kn + c0 * 8);
      }
    }
#pragma unroll
    for (int kk = 0; kk < 2; ++kk) {
      bf16x8 af[4], bfr[4];
#pragma unroll
      for (int m = 0; m < 4; ++m) {
        int row = wr * 64 + m * 16 + lc;
        int ch = kk * 4 + g;
        af[m] = *(const bf16x8*)&As[row * 64 + (((ch ^ (row & 7))) << 3)];
      }
#pragma unroll
      for (int n = 0; n < 4; ++n) {
        int row = wc * 64 + n * 16 + lc;
        int ch = kk * 4 + g;
        bfr[n] = *(const bf16x8*)&Bs[row * 64 + (((ch ^ (row & 7))) << 3)];
      }
#pragma unroll
      for (int m = 0; m < 4; ++m)
#pragma unroll
        for (int n = 0; n < 4; ++n)
          acc[m][n] = __builtin_amdgcn_mfma_f32_16x16x32_bf16(af[m], bfr[n], acc[m][n], 0, 0, 0);
    }
  }

  if (MODE == 0 || MODE == 2) {
    unsigned short* Ko = (unsigned short*)outp;
#pragma unroll
    for (int m = 0; m < 4; ++m)
#pragma unroll
      for (int n = 0; n < 4; ++n)
#pragma unroll
        for (int r = 0; r < 4; ++r) {
          int p = rowBase + wr * 64 + m * 16 + g * 4 + r;
          int f = colBase + wc * 64 + n * 16 + lc;
          int d = f & 63, h = f >> 6;
          float v = acc[m][n][r];
          float vo = __shfl_xor(v, 1);
          if (MODE == 0) {
            int b = p >> 12, nkv = p & 4095;
            float sn = rope[nkv * 128 + d], cs = rope[nkv * 128 + 64 + d];
            float o = (d & 1) ? fmaf(vo, sn, v * cs) : fmaf(-vo, sn, v * cs);
            Ko[((size_t)(b * NHEAD + h) * NKV + nkv) * 64 + d] = f2bf(o);
          } else {
            int b = p >> 8, nq = p & 255;
            float sn = rope[nq * 128 + d], cs = rope[nq * 128 + 64 + d];
            float o = (d & 1) ? fmaf(vo, sn, v * cs) : fmaf(-vo, sn, v * cs);
            Ko[((size_t)(b * NHEAD + h) * NQ + nq) * 64 + d] = f2bf(o * 0.125f);
          }
        }
  } else if (MODE == 1) {
    unsigned short* Vt = (unsigned short*)outp;
#pragma unroll
    for (int m = 0; m < 4; ++m)
#pragma unroll
      for (int n = 0; n < 4; ++n) {
        int p0 = rowBase + wr * 64 + m * 16 + g * 4;
        int b = p0 >> 12, nkv0 = p0 & 4095;
        int f = colBase + wc * 64 + n * 16 + lc;
        int d = f & 63, h = f >> 6;
        us4 wv{f2bf(acc[m][n][0]), f2bf(acc[m][n][1]), f2bf(acc[m][n][2]), f2bf(acc[m][n][3])};
        *(us4*)&Vt[((size_t)(b * NHEAD + h) * 64 + d) * NKV + nkv0] = wv;
      }
  } else {
    float* Co = (float*)outp;
#pragma unroll
    for (int m = 0; m < 4; ++m)
#pragma unroll
      for (int n = 0; n < 4; ++n)
#pragma unroll
        for (int r = 0; r < 4; ++r) {
          int p = rowBase + wr * 64 + m * 16 + g * 4 + r;
          int f = colBase + wc * 64 + n * 16 + lc;
          Co[(size_t)p * DIMF + f] = acc[m][n][r];
        }
  }
}

// ---------------- flash attention (R4: 16x16x32 swapped, in-reg P) ---------
// grid 768 XCD-swizzled; qt = logical&3 (64 q), bh = logical>>2.
// 2 waves x 32 q (m=0,1 blocks of 16). Lane (lc=lane&15, g=lane>>4):
//   S^T D-frag: q = lc, kv = 16c + 4g + r   (c = kv chunk 0..7)
//   PV B-frag built from OWN regs; V LDS columns permuted so A/B k-slots pair:
//   stored[d][32kb+8g+j] = V^T[d][32kb + 4g + (j&3) + 16*(j>>2)].
__launch_bounds__(128, 2)
__global__ void attn_kernel(const unsigned short* __restrict__ Qb,
                            const unsigned short* __restrict__ Kb,
                            const unsigned short* __restrict__ Vtb,
                            unsigned short* __restrict__ Ob) {
  __shared__ unsigned short Ks[128 * 64];    // [kv][d]  16KB, chunk ^= (kv&7)
  __shared__ unsigned short Vts[64 * 128];   // [d][kv'] 16KB, chunk ^= (d&15)
  const int logical = (blockIdx.x & 7) * 96 + (blockIdx.x >> 3);  // 768%8==0
  const int qt = logical & 3, bh = logical >> 2;
  const int b = bh / NHEAD, h = bh % NHEAD;
  const int t = threadIdx.x;
  const int lane = t & 63, w = t >> 6;
  const int g = lane >> 4, lc = lane & 15;
  const int qbase = qt * 64 + w * 32;

  // Q B-frags (verified layout): qf[m][kk] = Q[qbase+m*16+lc][kk*32 + g*8 ..]
  bf16x8 qf[2][2];
#pragma unroll
  for (int m = 0; m < 2; ++m)
#pragma unroll
    for (int kk = 0; kk < 2; ++kk)
      qf[m][kk] = *(const bf16x8*)(Qb + ((size_t)bh * NQ + qbase + m * 16 + lc) * 64 + kk * 32 + g * 8);

  const f32x4 z4 = {0.f, 0.f, 0.f, 0.f};
  f32x4 oacc[2][4];
#pragma unroll
  for (int m = 0; m < 2; ++m)
#pragma unroll
    for (int df = 0; df < 4; ++df) oacc[m][df] = z4;
  float mrun[2] = {-1e30f, -1e30f}, lrun[2] = {0.f, 0.f};

  // staging: K rows 16x8-chunk, V rows 8x16-chunk with column permutation
  const int r0 = t >> 3, c0 = t & 7;
  const int d0 = t >> 4, cv = t & 15;
  const int pbase = 32 * (cv >> 2) + 16 * (cv & 1) + 4 * ((cv >> 1) & 1);
  const int ch0 = pbase >> 3, of0 = pbase & 7;   // of0 in {0,4} shorts (8B aligned)
  const int ch1 = (pbase + 8) >> 3;

  u16x8 rk[8], rv[8];
#define LOAD_TILE(KT)                                                                        \
  do {                                                                                       \
    const int kvb = (KT) * 128;                                                              \
    _Pragma("unroll")                                                                        \
    for (int pp = 0; pp < 8; ++pp)                                                           \
      rk[pp] = *(const u16x8*)(Kb + ((size_t)bh * NKV + kvb + pp * 16 + r0) * 64 + c0 * 8);  \
    _Pragma("unroll")                                                                        \
    for (int pp = 0; pp < 8; ++pp)                                                           \
      rv[pp] = *(const u16x8*)(Vtb + ((size_t)bh * 64 + pp * 8 + d0) * NKV + kvb + cv * 8);  \
  } while (0)

  LOAD_TILE(0);

  for (int kt = 0; kt < 32; ++kt) {
    __syncthreads();   // previous tile's LDS reads complete
#pragma unroll
    for (int pp = 0; pp < 8; ++pp) {
      int row = pp * 16 + r0;
      *(u16x8*)&Ks[row * 64 + ((c0 ^ (row & 7)) << 3)] = rk[pp];
    }
#pragma unroll
    for (int pp = 0; pp < 8; ++pp) {
      int d = pp * 8 + d0;
      u16x4 lo = __builtin_shufflevector(rv[pp], rv[pp], 0, 1, 2, 3);
      u16x4 hi = __builtin_shufflevector(rv[pp], rv[pp], 4, 5, 6, 7);
      *(u16x4*)&Vts[d * 128 + ((ch0 ^ (d & 15)) << 3) + of0] = lo;
      *(u16x4*)&Vts[d * 128 + ((ch1 ^ (d & 15)) << 3) + of0] = hi;
    }
    if (kt + 1 < 32) LOAD_TILE(kt + 1);   // prefetch hides HBM latency
    __syncthreads();   // staging visible

    // S^T = K Q^T: s[m][c][r] = P-pre[kv=16c+4g+r][q = qbase+m*16+lc]
    f32x4 s[2][8];
#pragma unroll
    for (int m = 0; m < 2; ++m)
#pragma unroll
      for (int c = 0; c < 8; ++c) s[m][c] = z4;
#pragma unroll
    for (int kk = 0; kk < 2; ++kk)
#pragma unroll
      for (int c = 0; c < 8; ++c) {
        int row = c * 16 + lc;
        bf16x8 kf = *(const bf16x8*)&Ks[row * 64 + (((kk * 4 + g) ^ (row & 7)) << 3)];
        s[0][c] = __builtin_amdgcn_mfma_f32_16x16x32_bf16(kf, qf[0][kk], s[0][c], 0, 0, 0);
        s[1][c] = __builtin_amdgcn_mfma_f32_16x16x32_bf16(kf, qf[1][kk], s[1][c], 0, 0, 0);
      }

    // online softmax + in-register P pack (zero cross-lane for pack)
    uint32_t pk[2][8][2];
#pragma unroll
    for (int m = 0; m < 2; ++m) {
      float mx = s[m][0][0];
#pragma unroll
      for (int c = 0; c < 8; ++c)
#pragma unroll
        for (int r = 0; r < 4; ++r) mx = fmaxf(mx, s[m][c][r]);
      mx = fmaxf(mx, __shfl_xor(mx, 16));
      mx = fmaxf(mx, __shfl_xor(mx, 32));
      float nm = fmaxf(mrun[m], mx);
      float al = __expf(mrun[m] - nm);
      mrun[m] = nm;
      float ls = 0.f;
#pragma unroll
      for (int c = 0; c < 8; ++c)
#pragma unroll
        for (int r = 0; r < 4; ++r) {
          float p = __expf(s[m][c][r] - nm);
          s[m][c][r] = p;
          ls += p;
        }
      ls += __shfl_xor(ls, 16);
      ls += __shfl_xor(ls, 32);
      lrun[m] = lrun[m] * al + ls;
#pragma unroll
      for (int df = 0; df < 4; ++df)
#pragma unroll
        for (int r = 0; r < 4; ++r) oacc[m][df][r] *= al;
#pragma unroll
      for (int c = 0; c < 8; ++c)
#pragma unroll
        for (int w2 = 0; w2 < 2; ++w2) {
          float a = s[m][c][2 * w2], bb = s[m][c][2 * w2 + 1];
          asm("v_cvt_pk_bf16_f32 %0, %1, %2" : "=v"(pk[m][c][w2]) : "v"(a), "v"(bb));
        }
    }

    // PV: O^T[d][q] += Vperm * Pown  (A/B k-slots pair by construction)
#pragma unroll
    for (int kb = 0; kb < 4; ++kb) {
      union { uint32_t wd[4]; bf16x8 v; } pA, pB;
      pA.wd[0] = pk[0][2 * kb][0];     pA.wd[1] = pk[0][2 * kb][1];
      pA.wd[2] = pk[0][2 * kb + 1][0]; pA.wd[3] = pk[0][2 * kb + 1][1];
      pB.wd[0] = pk[1][2 * kb][0];     pB.wd[1] = pk[1][2 * kb][1];
      pB.wd[2] = pk[1][2 * kb + 1][0]; pB.wd[3] = pk[1][2 * kb + 1][1];
#pragma unroll
      for (int df = 0; df < 4; ++df) {
        int row = df * 16 + lc;
        bf16x8 vf = *(const bf16x8*)&Vts[row * 128 + (((kb * 4 + g) ^ (row & 15)) << 3)];
        oacc[0][df] = __builtin_amdgcn_mfma_f32_16x16x32_bf16(vf, pA.v, oacc[0][df], 0, 0, 0);
        oacc[1][df] = __builtin_amdgcn_mfma_f32_16x16x32_bf16(vf, pB.v, oacc[1][df], 0, 0, 0);
      }
    }
  }
#undef LOAD_TILE

  // epilogue: O[q][d], q = qbase+m*16+lc, d = df*16 + g*4 + r
#pragma unroll
  for (int m = 0; m < 2; ++m) {
    float inv = 1.0f / lrun[m];
    int q = qbase + m * 16 + lc;
#pragma unroll
    for (int df = 0; df < 4; ++df) {
      us4 wv{f2bf(oacc[m][df][0] * inv), f2bf(oacc[m][df][1] * inv),
             f2bf(oacc[m][df][2] * inv), f2bf(oacc[m][df][3] * inv)};
      *(us4*)&Ob[((size_t)b * NQ + q) * DIMF + h * 64 + df * 16 + g * 4] = wv;
    }
  }
}

// ---------------- launch ----------------------------------------------------
extern "C" void kernel_launch(void* const* d_in, const int* in_sizes, int n_in,
                              void* d_out, int out_size, void* d_ws, size_t ws_size,
                              hipStream_t stream) {
  const float* x      = (const float*)d_in[0];
  const float* ctx    = (const float*)d_in[1];
  const float* rope_q = (const float*)d_in[2];
  const float* rope_k = (const float*)d_in[3];
  const float* Wq     = (const float*)d_in[4];
  const float* Wk     = (const float*)d_in[5];
  const float* Wv     = (const float*)d_in[6];
  const float* Wo     = (const float*)d_in[7];

  char* ws = (char*)d_ws;
  const size_t SZ_CTXB = (size_t)NB * NKV * DIMF * 2;
  const size_t SZ_XB   = (size_t)NB * NQ * DIMF * 2;
  const size_t SZ_WT   = (size_t)DIMF * DIMF * 2;
  unsigned short* ctxb = (unsigned short*)(ws);
  unsigned short* ob   = (unsigned short*)(ws);                       // alias ctxb
  unsigned short* xb   = (unsigned short*)(ws + SZ_CTXB);
  unsigned short* wkt  = (unsigned short*)(ws + SZ_CTXB + SZ_XB);
  unsigned short* wvt  = (unsigned short*)(ws + SZ_CTXB + SZ_XB + SZ_WT);
  unsigned short* wqt  = (unsigned short*)(ws + SZ_CTXB + SZ_XB + 2 * SZ_WT);
  unsigned short* wot  = (unsigned short*)(ws + SZ_CTXB + SZ_XB + 3 * SZ_WT);
  unsigned short* kb   = (unsigned short*)(ws + SZ_CTXB + SZ_XB + 4 * SZ_WT);
  unsigned short* vtb  = (unsigned short*)(ws + SZ_CTXB + SZ_XB + 4 * SZ_WT + SZ_CTXB);
  unsigned short* qb   = (unsigned short*)(ws + SZ_CTXB + SZ_XB + 4 * SZ_WT + 2 * SZ_CTXB);

  cvt_kernel<<<dim3(2048), dim3(256), 0, stream>>>(ctx, ctxb, NB * NKV * DIMF);
  cvt_kernel<<<dim3(1024), dim3(256), 0, stream>>>(x, xb, NB * NQ * DIMF);
  twt_kernel<<<dim3(24, 24, 4), dim3(32, 8), 0, stream>>>(Wk, Wv, Wq, Wo, wkt, wvt, wqt, wot);

  gemm_kernel<0><<<dim3(512, 6), dim3(256), 0, stream>>>(ctxb, wkt, kb, rope_k);
  gemm_kernel<1><<<dim3(512, 6), dim3(256), 0, stream>>>(ctxb, wvt, vtb, nullptr);
  gemm_kernel<2><<<dim3(32, 6), dim3(256), 0, stream>>>(xb, wqt, qb, rope_q);

  attn_kernel<<<dim3(768), dim3(128), 0, stream>>>(qb, kb, vtb, ob);

  gemm_kernel<3><<<dim3(32, 6), dim3(256), 0, stream>>>(ob, wot, d_out, nullptr);
}

// Round 5
// 408.886 us; speedup vs baseline: 1.2876x; 1.2876x over previous
//
#include <hip/hip_runtime.h>
#include <stdint.h>

// ---------------------------------------------------------------------------
// CrossAttentionRope: x(16,256,768), ctx(16,4096,768) f32 -> out(16,256,768) f32
// R5: attn remapped — 4 waves/block (256 thr), each wave ONE 16-row q block
//     (R4's verified swapped-QK^T + in-reg P math, verbatim formulas),
//     bit_cast instead of union (no scratch), 12 waves/CU. GEMMs = R2 proven.
// ---------------------------------------------------------------------------

typedef __bf16 bf16x8 __attribute__((ext_vector_type(8)));
typedef unsigned short u16x8 __attribute__((ext_vector_type(8)));
typedef unsigned short u16x4 __attribute__((ext_vector_type(4)));
typedef uint32_t u32x4 __attribute__((ext_vector_type(4)));
typedef float f32x4 __attribute__((ext_vector_type(4)));

#define DIMF 768
#define NHEAD 12
#define NKV 4096
#define NQ 256
#define NB 16

struct alignas(8) us4 { unsigned short x, y, z, w; };

__device__ __forceinline__ unsigned short f2bf(float x) {
  uint32_t u = __float_as_uint(x);
  u += 0x7fffu + ((u >> 16) & 1u);   // round-to-nearest-even
  return (unsigned short)(u >> 16);
}

// ---------------- convert f32 -> bf16 (vectorized, grid-stride) ------------
__global__ void cvt_kernel(const float* __restrict__ in, unsigned short* __restrict__ out, int n) {
  int stride = gridDim.x * blockDim.x * 4;
  for (int i = (blockIdx.x * blockDim.x + threadIdx.x) * 4; i < n; i += stride) {
    float4 v = *(const float4*)(in + i);
    us4 o{f2bf(v.x), f2bf(v.y), f2bf(v.z), f2bf(v.w)};
    *(us4*)(out + i) = o;
  }
}

// ---------------- weight transpose + cvt: Wt[n][k] = W[k][n] ---------------
__global__ void twt_kernel(const float* __restrict__ W0, const float* __restrict__ W1,
                           const float* __restrict__ W2, const float* __restrict__ W3,
                           unsigned short* __restrict__ O0, unsigned short* __restrict__ O1,
                           unsigned short* __restrict__ O2, unsigned short* __restrict__ O3) {
  const float* W; unsigned short* O;
  switch (blockIdx.z) {
    case 0: W = W0; O = O0; break;
    case 1: W = W1; O = O1; break;
    case 2: W = W2; O = O2; break;
    default: W = W3; O = O3; break;
  }
  __shared__ float t[32][33];
  int x0 = blockIdx.x * 32, y0 = blockIdx.y * 32;
  int tx = threadIdx.x, ty = threadIdx.y;
#pragma unroll
  for (int j = 0; j < 4; ++j)
    t[ty + 8 * j][tx] = W[(size_t)(y0 + ty + 8 * j) * DIMF + x0 + tx];
  __syncthreads();
#pragma unroll
  for (int j = 0; j < 4; ++j)
    O[(size_t)(x0 + ty + 8 * j) * DIMF + y0 + tx] = f2bf(t[tx][ty + 8 * j]);
}

// ---------------- GEMM (R2-proven): C(128x128) = A(Mx768) * Bt(768x768)^T ---
template <int MODE>
__launch_bounds__(256, 2)
__global__ void gemm_kernel(const unsigned short* __restrict__ A,
                            const unsigned short* __restrict__ Bt,
                            void* __restrict__ outp,
                            const float* __restrict__ rope) {
  __shared__ unsigned short As[128 * 64];
  __shared__ unsigned short Bs[128 * 64];
  const int t = threadIdx.x;
  const int lane = t & 63, wid = t >> 6;
  const int g = lane >> 4, lc = lane & 15;
  const int wr = wid >> 1, wc = wid & 1;
  const int rowBase = blockIdx.x * 128, colBase = blockIdx.y * 128;

  const f32x4 z4 = {0.f, 0.f, 0.f, 0.f};
  f32x4 acc[4][4];
#pragma unroll
  for (int m = 0; m < 4; ++m)
#pragma unroll
    for (int n = 0; n < 4; ++n) acc[m][n] = z4;

  const int r0 = t >> 3;   // 0..31
  const int c0 = t & 7;    // 16B chunk within 128B row

  bf16x8 ra[4], rb[4];
#pragma unroll
  for (int pp = 0; pp < 4; ++pp) {
    int row = pp * 32 + r0;
    ra[pp] = *(const bf16x8*)(A + (size_t)(rowBase + row) * DIMF + c0 * 8);
    rb[pp] = *(const bf16x8*)(Bt + (size_t)(colBase + row) * DIMF + c0 * 8);
  }

  for (int kb = 0; kb < 12; ++kb) {
    __syncthreads();
#pragma unroll
    for (int pp = 0; pp < 4; ++pp) {
      int row = pp * 32 + r0;
      int ph = ((c0 ^ (row & 7)) << 3);
      *(bf16x8*)&As[row * 64 + ph] = ra[pp];
      *(bf16x8*)&Bs[row * 64 + ph] = rb[pp];
    }
    __syncthreads();
    if (kb + 1 < 12) {
      int kn = (kb + 1) * 64;
#pragma unroll
      for (int pp = 0; pp < 4; ++pp) {
        int row = pp * 32 + r0;
        ra[pp] = *(const bf16x8*)(A + (size_t)(rowBase + row) * DIMF + kn + c0 * 8);
        rb[pp] = *(const bf16x8*)(Bt + (size_t)(colBase + row) * DIMF + kn + c0 * 8);
      }
    }
#pragma unroll
    for (int kk = 0; kk < 2; ++kk) {
      bf16x8 af[4], bfr[4];
#pragma unroll
      for (int m = 0; m < 4; ++m) {
        int row = wr * 64 + m * 16 + lc;
        int ch = kk * 4 + g;
        af[m] = *(const bf16x8*)&As[row * 64 + (((ch ^ (row & 7))) << 3)];
      }
#pragma unroll
      for (int n = 0; n < 4; ++n) {
        int row = wc * 64 + n * 16 + lc;
        int ch = kk * 4 + g;
        bfr[n] = *(const bf16x8*)&Bs[row * 64 + (((ch ^ (row & 7))) << 3)];
      }
#pragma unroll
      for (int m = 0; m < 4; ++m)
#pragma unroll
        for (int n = 0; n < 4; ++n)
          acc[m][n] = __builtin_amdgcn_mfma_f32_16x16x32_bf16(af[m], bfr[n], acc[m][n], 0, 0, 0);
    }
  }

  if (MODE == 0 || MODE == 2) {
    unsigned short* Ko = (unsigned short*)outp;
#pragma unroll
    for (int m = 0; m < 4; ++m)
#pragma unroll
      for (int n = 0; n < 4; ++n)
#pragma unroll
        for (int r = 0; r < 4; ++r) {
          int p = rowBase + wr * 64 + m * 16 + g * 4 + r;
          int f = colBase + wc * 64 + n * 16 + lc;
          int d = f & 63, h = f >> 6;
          float v = acc[m][n][r];
          float vo = __shfl_xor(v, 1);
          if (MODE == 0) {
            int b = p >> 12, nkv = p & 4095;
            float sn = rope[nkv * 128 + d], cs = rope[nkv * 128 + 64 + d];
            float o = (d & 1) ? fmaf(vo, sn, v * cs) : fmaf(-vo, sn, v * cs);
            Ko[((size_t)(b * NHEAD + h) * NKV + nkv) * 64 + d] = f2bf(o);
          } else {
            int b = p >> 8, nq = p & 255;
            float sn = rope[nq * 128 + d], cs = rope[nq * 128 + 64 + d];
            float o = (d & 1) ? fmaf(vo, sn, v * cs) : fmaf(-vo, sn, v * cs);
            Ko[((size_t)(b * NHEAD + h) * NQ + nq) * 64 + d] = f2bf(o * 0.125f);
          }
        }
  } else if (MODE == 1) {
    unsigned short* Vt = (unsigned short*)outp;
#pragma unroll
    for (int m = 0; m < 4; ++m)
#pragma unroll
      for (int n = 0; n < 4; ++n) {
        int p0 = rowBase + wr * 64 + m * 16 + g * 4;
        int b = p0 >> 12, nkv0 = p0 & 4095;
        int f = colBase + wc * 64 + n * 16 + lc;
        int d = f & 63, h = f >> 6;
        us4 wv{f2bf(acc[m][n][0]), f2bf(acc[m][n][1]), f2bf(acc[m][n][2]), f2bf(acc[m][n][3])};
        *(us4*)&Vt[((size_t)(b * NHEAD + h) * 64 + d) * NKV + nkv0] = wv;
      }
  } else {
    float* Co = (float*)outp;
#pragma unroll
    for (int m = 0; m < 4; ++m)
#pragma unroll
      for (int n = 0; n < 4; ++n)
#pragma unroll
        for (int r = 0; r < 4; ++r) {
          int p = rowBase + wr * 64 + m * 16 + g * 4 + r;
          int f = colBase + wc * 64 + n * 16 + lc;
          Co[(size_t)p * DIMF + f] = acc[m][n][r];
        }
  }
}

// ---------------- flash attention (R5: 4 waves, 16q each, in-reg P) --------
// grid 768 XCD-swizzled; qt = logical&3 (64 q), bh = logical>>2.
// Wave w handles q rows [qt*64 + w*16, +16). Lane (lc=lane&15, g=lane>>4):
//   S^T D-frag: q = qrow(lc), kv = 16c + 4g + r   (verified in R4)
//   PV B-frag from OWN regs; V LDS column-permuted (verified in R4):
//   stored[d][32kb+8g+j] = V^T[d][32kb + 4g + (j&3) + 16*(j>>2)].
__launch_bounds__(256, 2)
__global__ void attn_kernel(const unsigned short* __restrict__ Qb,
                            const unsigned short* __restrict__ Kb,
                            const unsigned short* __restrict__ Vtb,
                            unsigned short* __restrict__ Ob) {
  __shared__ unsigned short Ks[128 * 64];    // [kv][d]  16KB, chunk ^= (kv&7)
  __shared__ unsigned short Vts[64 * 128];   // [d][kv'] 16KB, chunk ^= (d&15)
  const int logical = (blockIdx.x & 7) * 96 + (blockIdx.x >> 3);  // 768%8==0
  const int qt = logical & 3, bh = logical >> 2;
  const int b = bh / NHEAD, h = bh % NHEAD;
  const int t = threadIdx.x;
  const int lane = t & 63, w = t >> 6;       // w = 0..3
  const int g = lane >> 4, lc = lane & 15;
  const int qrow = qt * 64 + w * 16 + lc;    // this wave's q row for this lane

  // Q B-frags (verified): qf[kk] = Q[qrow][kk*32 + g*8 ..]
  bf16x8 qf[2];
#pragma unroll
  for (int kk = 0; kk < 2; ++kk)
    qf[kk] = *(const bf16x8*)(Qb + ((size_t)bh * NQ + qrow) * 64 + kk * 32 + g * 8);

  const f32x4 z4 = {0.f, 0.f, 0.f, 0.f};
  f32x4 oacc[4];
#pragma unroll
  for (int df = 0; df < 4; ++df) oacc[df] = z4;
  float mrun = -1e30f, lrun = 0.f;

  // staging across 256 threads: K 128x64 (4 passes of 32 rows), V 64x128
  // (4 passes of 16 d-rows, column-permuted)
  const int r0 = t >> 3, c0 = t & 7;
  const int d0 = t >> 4, cv = t & 15;
  const int pbase = 32 * (cv >> 2) + 16 * (cv & 1) + 4 * ((cv >> 1) & 1);
  const int ch0 = pbase >> 3, of0 = pbase & 7;   // of0 in {0,4} shorts (8B aligned)
  const int ch1 = (pbase + 8) >> 3;

  u16x8 rk[4], rv[4];
#define LOAD_TILE(KT)                                                                        \
  do {                                                                                       \
    const int kvb = (KT) * 128;                                                              \
    _Pragma("unroll")                                                                        \
    for (int pp = 0; pp < 4; ++pp)                                                           \
      rk[pp] = *(const u16x8*)(Kb + ((size_t)bh * NKV + kvb + pp * 32 + r0) * 64 + c0 * 8);  \
    _Pragma("unroll")                                                                        \
    for (int pp = 0; pp < 4; ++pp)                                                           \
      rv[pp] = *(const u16x8*)(Vtb + ((size_t)bh * 64 + pp * 16 + d0) * NKV + kvb + cv * 8); \
  } while (0)

  LOAD_TILE(0);

  for (int kt = 0; kt < 32; ++kt) {
    __syncthreads();   // previous tile's LDS reads complete
#pragma unroll
    for (int pp = 0; pp < 4; ++pp) {
      int row = pp * 32 + r0;
      *(u16x8*)&Ks[row * 64 + ((c0 ^ (row & 7)) << 3)] = rk[pp];
    }
#pragma unroll
    for (int pp = 0; pp < 4; ++pp) {
      int d = pp * 16 + d0;
      u16x4 lo = __builtin_shufflevector(rv[pp], rv[pp], 0, 1, 2, 3);
      u16x4 hi = __builtin_shufflevector(rv[pp], rv[pp], 4, 5, 6, 7);
      *(u16x4*)&Vts[d * 128 + ((ch0 ^ (d & 15)) << 3) + of0] = lo;
      *(u16x4*)&Vts[d * 128 + ((ch1 ^ (d & 15)) << 3) + of0] = hi;
    }
    if (kt + 1 < 32) LOAD_TILE(kt + 1);   // prefetch hides HBM latency
    __syncthreads();   // staging visible

    // S^T = K Q^T: s[c][r] = P-pre[kv=16c+4g+r][q = qrow]
    f32x4 s[8];
#pragma unroll
    for (int c = 0; c < 8; ++c) s[c] = z4;
#pragma unroll
    for (int kk = 0; kk < 2; ++kk)
#pragma unroll
      for (int c = 0; c < 8; ++c) {
        int row = c * 16 + lc;
        bf16x8 kf = *(const bf16x8*)&Ks[row * 64 + (((kk * 4 + g) ^ (row & 7)) << 3)];
        s[c] = __builtin_amdgcn_mfma_f32_16x16x32_bf16(kf, qf[kk], s[c], 0, 0, 0);
      }

    // online softmax (row data spread over g-groups at same lc: xor 16, 32)
    float mx = s[0][0];
#pragma unroll
    for (int c = 0; c < 8; ++c)
#pragma unroll
      for (int r = 0; r < 4; ++r) mx = fmaxf(mx, s[c][r]);
    mx = fmaxf(mx, __shfl_xor(mx, 16));
    mx = fmaxf(mx, __shfl_xor(mx, 32));
    float nm = fmaxf(mrun, mx);
    float al = __expf(mrun - nm);
    mrun = nm;
    float ls = 0.f;
#pragma unroll
    for (int c = 0; c < 8; ++c)
#pragma unroll
      for (int r = 0; r < 4; ++r) {
        float p = __expf(s[c][r] - nm);
        s[c][r] = p;
        ls += p;
      }
    ls += __shfl_xor(ls, 16);
    ls += __shfl_xor(ls, 32);
    lrun = lrun * al + ls;
#pragma unroll
    for (int df = 0; df < 4; ++df)
#pragma unroll
      for (int r = 0; r < 4; ++r) oacc[df][r] *= al;

    // pack P in-register (zero cross-lane)
    uint32_t pk[8][2];
#pragma unroll
    for (int c = 0; c < 8; ++c)
#pragma unroll
      for (int w2 = 0; w2 < 2; ++w2) {
        float a = s[c][2 * w2], bb = s[c][2 * w2 + 1];
        asm("v_cvt_pk_bf16_f32 %0, %1, %2" : "=v"(pk[c][w2]) : "v"(a), "v"(bb));
      }

    // PV: O^T += Vperm * Pown (A/B k-slots pair by construction, verified R4)
#pragma unroll
    for (int kb = 0; kb < 4; ++kb) {
      u32x4 pw = {pk[2 * kb][0], pk[2 * kb][1], pk[2 * kb + 1][0], pk[2 * kb + 1][1]};
      bf16x8 pa = __builtin_bit_cast(bf16x8, pw);
#pragma unroll
      for (int df = 0; df < 4; ++df) {
        int row = df * 16 + lc;
        bf16x8 vf = *(const bf16x8*)&Vts[row * 128 + (((kb * 4 + g) ^ (row & 15)) << 3)];
        oacc[df] = __builtin_amdgcn_mfma_f32_16x16x32_bf16(vf, pa, oacc[df], 0, 0, 0);
      }
    }
  }
#undef LOAD_TILE

  // epilogue: O[qrow][d], d = df*16 + g*4 + r
  float inv = 1.0f / lrun;
#pragma unroll
  for (int df = 0; df < 4; ++df) {
    us4 wv{f2bf(oacc[df][0] * inv), f2bf(oacc[df][1] * inv),
           f2bf(oacc[df][2] * inv), f2bf(oacc[df][3] * inv)};
    *(us4*)&Ob[((size_t)b * NQ + qrow) * DIMF + h * 64 + df * 16 + g * 4] = wv;
  }
}

// ---------------- launch ----------------------------------------------------
extern "C" void kernel_launch(void* const* d_in, const int* in_sizes, int n_in,
                              void* d_out, int out_size, void* d_ws, size_t ws_size,
                              hipStream_t stream) {
  const float* x      = (const float*)d_in[0];
  const float* ctx    = (const float*)d_in[1];
  const float* rope_q = (const float*)d_in[2];
  const float* rope_k = (const float*)d_in[3];
  const float* Wq     = (const float*)d_in[4];
  const float* Wk     = (const float*)d_in[5];
  const float* Wv     = (const float*)d_in[6];
  const float* Wo     = (const float*)d_in[7];

  char* ws = (char*)d_ws;
  const size_t SZ_CTXB = (size_t)NB * NKV * DIMF * 2;
  const size_t SZ_XB   = (size_t)NB * NQ * DIMF * 2;
  const size_t SZ_WT   = (size_t)DIMF * DIMF * 2;
  unsigned short* ctxb = (unsigned short*)(ws);
  unsigned short* ob   = (unsigned short*)(ws);                       // alias ctxb
  unsigned short* xb   = (unsigned short*)(ws + SZ_CTXB);
  unsigned short* wkt  = (unsigned short*)(ws + SZ_CTXB + SZ_XB);
  unsigned short* wvt  = (unsigned short*)(ws + SZ_CTXB + SZ_XB + SZ_WT);
  unsigned short* wqt  = (unsigned short*)(ws + SZ_CTXB + SZ_XB + 2 * SZ_WT);
  unsigned short* wot  = (unsigned short*)(ws + SZ_CTXB + SZ_XB + 3 * SZ_WT);
  unsigned short* kb   = (unsigned short*)(ws + SZ_CTXB + SZ_XB + 4 * SZ_WT);
  unsigned short* vtb  = (unsigned short*)(ws + SZ_CTXB + SZ_XB + 4 * SZ_WT + SZ_CTXB);
  unsigned short* qb   = (unsigned short*)(ws + SZ_CTXB + SZ_XB + 4 * SZ_WT + 2 * SZ_CTXB);

  cvt_kernel<<<dim3(2048), dim3(256), 0, stream>>>(ctx, ctxb, NB * NKV * DIMF);
  cvt_kernel<<<dim3(1024), dim3(256), 0, stream>>>(x, xb, NB * NQ * DIMF);
  twt_kernel<<<dim3(24, 24, 4), dim3(32, 8), 0, stream>>>(Wk, Wv, Wq, Wo, wkt, wvt, wqt, wot);

  gemm_kernel<0><<<dim3(512, 6), dim3(256), 0, stream>>>(ctxb, wkt, kb, rope_k);
  gemm_kernel<1><<<dim3(512, 6), dim3(256), 0, stream>>>(ctxb, wvt, vtb, nullptr);
  gemm_kernel<2><<<dim3(32, 6), dim3(256), 0, stream>>>(xb, wqt, qb, rope_q);

  attn_kernel<<<dim3(768), dim3(256), 0, stream>>>(qb, kb, vtb, ob);

  gemm_kernel<3><<<dim3(32, 6), dim3(256), 0, stream>>>(ob, wot, d_out, nullptr);
}